// Round 9
// baseline (373.179 us; speedup 1.0000x reference)
//
#include <hip/hip_runtime.h>

// Problem constants (fixed by the reference).
#define D      256        // vq_embed_dim == C
#define N_E    16384      // codebook size
#define NPTS   8192       // B*H*W
#define ZOUT   2097152    // elements of z_hat_out
#define MARGIN 2.0e-2f    // cert/rescan margin ~6.6 sigma of bf16 pair error
#define BIGF   3.0e38f

typedef short bf16x8 __attribute__((ext_vector_type(8)));
typedef unsigned short us8 __attribute__((ext_vector_type(8)));
typedef float f32x16 __attribute__((ext_vector_type(16)));
typedef unsigned long long u64;

__device__ __forceinline__ unsigned short f2bf(float x) {  // RNE
    unsigned int u = __float_as_uint(x);
    return (unsigned short)((u + 0x7FFFu + ((u >> 16) & 1u)) >> 16);
}
__device__ __forceinline__ unsigned int mono(float f) {     // order-preserving
    unsigned int u = __float_as_uint(f);
    return (u & 0x80000000u) ? ~u : (u | 0x80000000u);
}
__device__ __forceinline__ float demono(unsigned int u) {
    return __uint_as_float((u & 0x80000000u) ? (u ^ 0x80000000u) : ~u);
}
__device__ __forceinline__ void gl_lds16(const void* g, void* l) {
    __builtin_amdgcn_global_load_lds(
        (const __attribute__((address_space(1))) unsigned int*)g,
        (__attribute__((address_space(3))) unsigned int*)l, 16, 0, 0);
}

// ---------------------------------------------------------------------------
// Fused prep. Blocks [0,256): z (32 points). Blocks [256,768): emb (32 codes).
// Zpk = bf16(-2z), Epk = bf16(emb) in fragment-chunk layout (chunk (g,ks):
// 64 lanes x 16B, lane = (row&31) + ((k&15)>>3)*32, elems k&7).
// e2[j] = |emb_j|^2 fp32; e2f = e2 permuted to MFMA C-row order.
// ---------------------------------------------------------------------------
__global__ __launch_bounds__(256) void prep(
    const float* __restrict__ z, const float* __restrict__ emb,
    unsigned short* __restrict__ Zpk, unsigned short* __restrict__ Epk,
    float* __restrict__ e2, float* __restrict__ e2f) {
    const int t = threadIdx.x;
    if (blockIdx.x < 256) {
        const int n0 = blockIdx.x * 32;
        const int p = t & 31, ks8 = t >> 5;     // 8 k-slabs of 32
        const int n = n0 + p;
        const int b = n >> 10, hw = n & 1023;
        const float* zb = z + (size_t)b * 262144 + hw;
        const int k0 = ks8 * 32;
        float v[32];
        #pragma unroll
        for (int kk = 0; kk < 32; ++kk)
            v[kk] = zb[(size_t)(k0 + kk) * 1024];   // coalesced in p
        const int g = n >> 5;
        #pragma unroll
        for (int i = 0; i < 4; ++i) {               // 4 us8 per 32-k slab
            us8 hv;
            #pragma unroll
            for (int c = 0; c < 8; ++c) hv[c] = f2bf(-2.0f * v[i * 8 + c]);
            const int kabs = k0 + i * 8;
            const int ks = kabs >> 4;
            const int l = p + ((kabs >> 3) & 1) * 32;
            *(us8*)(Zpk + ((size_t)(g * 16 + ks) * 64 + l) * 8) = hv;
        }
    } else {
        const int j0 = (blockIdx.x - 256) * 32;
        const int jl = t >> 3, q = t & 7;           // 8 k-slabs of 32
        const int jj = j0 + jl;
        const float* row = emb + (size_t)jj * D + q * 32;
        float v[32];
        float s = 0.f;
        #pragma unroll
        for (int i = 0; i < 8; ++i) {
            const float4 x = *(const float4*)(row + i * 4);
            v[i * 4] = x.x; v[i * 4 + 1] = x.y; v[i * 4 + 2] = x.z; v[i * 4 + 3] = x.w;
            s += x.x * x.x + x.y * x.y + x.z * x.z + x.w * x.w;
        }
        const int g = jj >> 5;
        #pragma unroll
        for (int i = 0; i < 4; ++i) {
            us8 hv;
            #pragma unroll
            for (int c = 0; c < 8; ++c) hv[c] = f2bf(v[i * 8 + c]);
            const int kabs = q * 32 + i * 8;
            const int ks = kabs >> 4;
            const int l = jl + ((kabs >> 3) & 1) * 32;
            *(us8*)(Epk + ((size_t)(g * 16 + ks) * 64 + l) * 8) = hv;
        }
        s += __shfl_xor(s, 1);
        s += __shfl_xor(s, 2);
        s += __shfl_xor(s, 4);
        if (q == 0) {
            e2[jj] = s;
            const int c5 = jj & 31;
            const int l5 = (c5 >> 2) & 1;
            const int r = (c5 & 3) | (((c5 >> 3) & 3) << 2);
            e2f[g * 32 + l5 * 16 + r] = s;
        }
    }
}

// ---------------------------------------------------------------------------
// GEMM + per-(point, 64-code group) top-2. Block: 256 thr = 4 waves, 128 pts
// (LDS, staged once) x 4 strips of 256 codes; wave wid owns a distinct
// 64-code column per strip. Depth-2 E prefetch (global), depth-1 Z (LDS).
// Register-budgeted epilogue: one code-frag at a time -> 4-level tournament
// (8-entry arrays) -> 3 running scalars per j. No arrays live across loops.
// Key u64 = mono(m1)<<32 | dq<<16 | code16, staged in swizzled LDS keybuf,
// flushed as one contiguous 16 KB block.
// C/D layout: col(point)=lane&31, row(code)=(r&3)+8*(r>>2)+4*(lane>>5).
// ---------------------------------------------------------------------------
__global__ __launch_bounds__(256, 2) void mfma_gemm(
    const unsigned short* __restrict__ Epk, const unsigned short* __restrict__ Zpk,
    const float* __restrict__ e2f, u64* __restrict__ tkey2) {
    __shared__ unsigned short Zbuf[64 * 512];   // 64 KB
    __shared__ u64 keybuf[128 * 16];            // 16 KB (col-swizzled)

    const int tid = threadIdx.x, lane = tid & 63, wid = tid >> 6;
    const int c32 = lane & 31, l5 = lane >> 5;
    const int n0 = blockIdx.x * 128;
    const int cs0 = blockIdx.y * 1024;

    #pragma unroll
    for (int ks = 0; ks < 16; ++ks)
        gl_lds16(Zpk + ((size_t)((n0 >> 5) + wid) * 16 + ks) * 512 + lane * 8,
                 Zbuf + (wid * 16 + ks) * 512);
    __syncthreads();   // single drain per block

    const unsigned short* zb = Zbuf + lane * 8;

    for (int s = 0; s < 4; ++s) {
        const int cb = cs0 + s * 256 + wid * 64;   // this wave's 64 codes
        const unsigned short* eb = Epk + ((size_t)(cb >> 5) * 16) * 512 + lane * 8;

        f32x16 acc[2][4];
        const f32x16 z16 = {0.f};
        #pragma unroll
        for (int i = 0; i < 2; ++i)
            #pragma unroll
            for (int j = 0; j < 4; ++j) acc[i][j] = z16;

        // E: depth-2 prefetch queue; Z: depth-1.
        bf16x8 e0[2], e1[2], pc[4], pn[4];
        #pragma unroll
        for (int i = 0; i < 2; ++i) {
            e0[i] = *(const bf16x8*)(eb + (i * 16 + 0) * 512);
            e1[i] = *(const bf16x8*)(eb + (i * 16 + 1) * 512);
        }
        #pragma unroll
        for (int j = 0; j < 4; ++j) pc[j] = *(const bf16x8*)(zb + (j * 16) * 512);

        #pragma unroll
        for (int ks = 0; ks < 16; ++ks) {
            bf16x8 e2q[2];
            if (ks < 14) {
                e2q[0] = *(const bf16x8*)(eb + (ks + 2) * 512);
                e2q[1] = *(const bf16x8*)(eb + (16 + ks + 2) * 512);
            }
            if (ks < 15) {
                #pragma unroll
                for (int j = 0; j < 4; ++j)
                    pn[j] = *(const bf16x8*)(zb + (j * 16 + ks + 1) * 512);
            }
            #pragma unroll
            for (int j = 0; j < 4; ++j) {
                acc[0][j] = __builtin_amdgcn_mfma_f32_32x32x16_bf16(
                    e0[0], pc[j], acc[0][j], 0, 0, 0);
                acc[1][j] = __builtin_amdgcn_mfma_f32_32x32x16_bf16(
                    e0[1], pc[j], acc[1][j], 0, 0, 0);
            }
            if (ks < 15) {
                e0[0] = e1[0]; e0[1] = e1[1];
                if (ks < 14) { e1[0] = e2q[0]; e1[1] = e2q[1]; }
                #pragma unroll
                for (int j = 0; j < 4; ++j) pc[j] = pn[j];
            }
        }

        const int gs = s * 4 + wid;
        #pragma unroll
        for (int j = 0; j < 4; ++j) {
            float a1 = BIGF, a2 = BIGF;
            int ai = 0;
            #pragma unroll
            for (int i = 0; i < 2; ++i) {
                // v = e2f + acc, consumed immediately (no long-lived arrays).
                const float* ep = e2f + ((cb >> 5) + i) * 32 + l5 * 16;
                float v[16];
                #pragma unroll
                for (int rq = 0; rq < 4; ++rq) {
                    const float4 q = *(const float4*)(ep + rq * 4);
                    v[rq * 4 + 0] = q.x + acc[i][j][rq * 4 + 0];
                    v[rq * 4 + 1] = q.y + acc[i][j][rq * 4 + 1];
                    v[rq * 4 + 2] = q.z + acc[i][j][rq * 4 + 2];
                    v[rq * 4 + 3] = q.w + acc[i][j][rq * 4 + 3];
                }
                // Level 0: pairs (2rp, 2rp+1); code(2rp+1) = code(2rp)+1.
                float m1[8], m2[8];
                int i1[8];
                #pragma unroll
                for (int rp = 0; rp < 8; ++rp) {
                    const float a = v[2 * rp], b = v[2 * rp + 1];
                    const bool aw = a <= b;               // tie -> lower code
                    m1[rp] = aw ? a : b;
                    m2[rp] = aw ? b : a;
                    const int ca = ((2 * rp) & 3) + 8 * ((2 * rp) >> 2);
                    i1[rp] = aw ? ca : ca + 1;
                }
                // Levels 1..3: a-side always holds lower codes.
                #pragma unroll
                for (int st = 1; st < 8; st <<= 1)
                    #pragma unroll
                    for (int t8 = 0; t8 < 8; t8 += 2 * st) {
                        const bool aw = m1[t8] <= m1[t8 + st];
                        m2[t8] = fminf(aw ? m2[t8] : m2[t8 + st],
                                       aw ? m1[t8 + st] : m1[t8]);
                        m1[t8] = aw ? m1[t8] : m1[t8 + st];
                        i1[t8] = aw ? i1[t8] : i1[t8 + st];
                    }
                const float f1 = m1[0], f2 = m2[0];
                const int fi = i * 32 + i1[0] + 4 * l5;
                const bool w = f1 < a1;   // i ascending = codes ascending
                a2 = fminf(w ? a1 : a2, w ? f2 : f1);
                a1 = w ? f1 : a1;
                ai = w ? fi : ai;
            }
            // Cross-half merge (tie degrades m2 -> uncertified -> exact path).
            const float o1 = __shfl_xor(a1, 32);
            const float o2 = __shfl_xor(a2, 32);
            const int oi = __shfl_xor(ai, 32);
            if (o1 < a1) { a2 = fminf(a1, o2); a1 = o1; ai = oi; }
            else         { a2 = fminf(a2, o1); }
            if (l5 == 0) {
                const unsigned int dq = (unsigned int)fminf(
                    fmaxf((a2 - a1) * 4096.0f, 0.0f), 65535.0f);
                const unsigned int code = (unsigned int)(cb + ai);
                const int p = j * 32 + c32;
                keybuf[p * 16 + ((gs + p) & 15)] =
                    ((u64)mono(a1) << 32) | (dq << 16) | code;
            }
        }
    }

    __syncthreads();
    // Flush: contiguous 16 KB block write, de-swizzling columns.
    u64* dst = tkey2 + (size_t)blockIdx.y * (NPTS * 16) + (size_t)n0 * 16;
    #pragma unroll
    for (int it = 0; it < 8; ++it) {
        const int idx = it * 256 + tid;
        const int p = idx >> 4, gl = idx & 15;
        dst[idx] = keybuf[p * 16 + ((gl + p) & 15)];
    }
}

// ---------------------------------------------------------------------------
// Rescore with certification. One wave per point. Lane l holds 4 group keys.
// d1/idx from global min key; d2 from second-best estimate. Certified if
// d2-d1 > MARGIN; else exact fp32 rescan of qualifying 64-code groups,
// lane-cooperative (coalesced 1KB/code rows, butterfly-reduced dot).
// ---------------------------------------------------------------------------
__global__ __launch_bounds__(256) void rescore(
    const u64* __restrict__ tkey2, const float* __restrict__ z,
    const float* __restrict__ emb, const float* __restrict__ e2,
    int* __restrict__ idxf, float* __restrict__ out_idx,
    float* __restrict__ loss) {
    const int tid = threadIdx.x, lane = tid & 63, w = tid >> 6;
    const int n = blockIdx.x * 4 + w;
    if (blockIdx.x == 0 && tid == 0) loss[0] = 0.f;

    const int gb = lane >> 2, q4 = lane & 3;
    u64 kv[4];
    {
        const u64* src = tkey2 + (size_t)gb * (NPTS * 16) + (size_t)n * 16 + q4 * 4;
        #pragma unroll
        for (int qq = 0; qq < 4; ++qq) kv[qq] = src[qq];
    }
    u64 k1 = kv[0];
    #pragma unroll
    for (int qq = 1; qq < 4; ++qq) k1 = kv[qq] < k1 ? kv[qq] : k1;
    #pragma unroll
    for (int st = 1; st < 64; st <<= 1) {
        const u64 o = __shfl_xor(k1, st);
        if (o < k1) k1 = o;
    }
    const float d1 = demono((unsigned int)(k1 >> 32));
    float d2 = BIGF;
    #pragma unroll
    for (int qq = 0; qq < 4; ++qq) {
        const float m1g = demono((unsigned int)(kv[qq] >> 32));
        const float cand = (kv[qq] == k1)
            ? d1 + (float)((kv[qq] >> 16) & 0xFFFFull) * (1.0f / 4096.0f)
            : m1g;
        d2 = fminf(d2, cand);
    }
    #pragma unroll
    for (int st = 1; st < 64; st <<= 1) d2 = fminf(d2, __shfl_xor(d2, st));

    int bi;
    if (d2 - d1 > MARGIN) {
        bi = (int)(unsigned int)(k1 & 0xFFFFull);       // certified
    } else {
        // Lane l holds residual components k = 4l..4l+3.
        const int b = n >> 10, hw = n & 1023;
        float r4[4];
        #pragma unroll
        for (int kk = 0; kk < 4; ++kk)
            r4[kk] = z[(size_t)b * 262144 + (size_t)(lane * 4 + kk) * 1024 + hw];
        const float thresh = d1 + MARGIN;
        u64 best = ~0ull;
        #pragma unroll
        for (int qq = 0; qq < 4; ++qq) {
            u64 mask = __ballot(demono((unsigned int)(kv[qq] >> 32)) <= thresh);
            while (mask) {
                const int bit = (int)__builtin_ctzll(mask);
                mask &= mask - 1;
                const int grp = (bit >> 2) * 16 + (bit & 3) * 4 + qq;
                const float* ebase = emb + (size_t)grp * (64 * D) + lane * 4;
                for (int ci = 0; ci < 64; ++ci) {
                    const float4 ev = *(const float4*)(ebase + ci * D);
                    float s = r4[0] * ev.x + r4[1] * ev.y +
                              r4[2] * ev.z + r4[3] * ev.w;
                    #pragma unroll
                    for (int st = 1; st < 64; st <<= 1) s += __shfl_xor(s, st);
                    const int code = grp * 64 + ci;
                    const float d = e2[code] - 2.0f * s;
                    const u64 key = ((u64)mono(d) << 32) | (unsigned int)code;
                    if (key < best) best = key;   // uniform across the wave
                }
            }
        }
        bi = (int)(unsigned int)(best & 0xFFFFFFFFull);
    }
    if (lane == 0) {
        idxf[n] = bi;
        const int b = n >> 10, hw = n & 1023;
        const float fv = (float)bi;
        #pragma unroll
        for (int sc = 0; sc < 4; ++sc) out_idx[b * 4096 + sc * 1024 + hw] = fv;
    }
}

// ---------------------------------------------------------------------------
// Gather q = emb[idx]; z_hat_out = z + (4q - z); loss accumulation.
// 1024 blocks: (4 c-tiles of 64) x (8 b x 32 hw-tiles). 256 thr = 32 hw x 8 cg.
// ---------------------------------------------------------------------------
__global__ __launch_bounds__(256) void quant_loss(
    const float* __restrict__ z, const float* __restrict__ emb,
    const int* __restrict__ idxf, float* __restrict__ out,
    float* __restrict__ loss) {
    __shared__ int idx_l[32];
    __shared__ float wsum[4];
    const int blk = blockIdx.x;
    const int c0 = (blk >> 8) * 64;
    const int rem = blk & 255;
    const int b = rem >> 5, hw0 = (rem & 31) * 32;
    const int t = threadIdx.x, hw_l = t & 31, cg = t >> 5;
    if (t < 32) idx_l[t] = idxf[b * 1024 + hw0 + t];
    __syncthreads();
    const int j = idx_l[hw_l];
    const float* er = emb + (size_t)j * D + c0 + cg * 8;
    const float4 q0 = *(const float4*)er;
    const float4 q1 = *(const float4*)(er + 4);
    const float qv[8] = {q0.x, q0.y, q0.z, q0.w, q1.x, q1.y, q1.z, q1.w};
    float e = 0.f;
    #pragma unroll
    for (int cc = 0; cc < 8; ++cc) {
        const int c = c0 + cg * 8 + cc;
        const size_t zi = (size_t)b * 262144 + (size_t)c * 1024 + hw0 + hw_l;
        const float zv = z[zi];
        const float q = qv[cc];
        const float zh = ((q + q) + q) + q;   // mimic 4-step accumulation
        out[zi] = zv + (zh - zv);
        e += 30.0f * q * q - 20.0f * q * zv + 4.0f * zv * zv;
    }
    #pragma unroll
    for (int off = 32; off > 0; off >>= 1) e += __shfl_down(e, off);
    if ((t & 63) == 0) wsum[t >> 6] = e;
    __syncthreads();
    if (t == 0) {
        const float s = wsum[0] + wsum[1] + wsum[2] + wsum[3];
        atomicAdd(loss, s * (0.3125f / 2097152.0f));
    }
}

// ---------------------------------------------------------------------------
extern "C" void kernel_launch(void* const* d_in, const int* in_sizes, int n_in,
                              void* d_out, int out_size, void* d_ws, size_t ws_size,
                              hipStream_t stream) {
    const float* z = (const float*)d_in[0];     // [8,256,32,32]
    const float* emb = (const float*)d_in[1];   // [16384,256]
    float* out = (float*)d_out;                 // z_hat_out | loss | total_idx

    // Workspace (~29.5 MB)
    unsigned short* Zpk = (unsigned short*)d_ws;            // 8192*256 bf16
    unsigned short* Epk = Zpk + (size_t)NPTS * D;           // 16384*256 bf16
    float* e2 = (float*)(Epk + (size_t)N_E * D);            // 16384 f32
    float* e2f = e2 + N_E;                                  // 16384 f32
    u64* tkey2 = (u64*)(e2f + N_E);                         // 16*8192*16 u64
    int* idxf = (int*)(tkey2 + (size_t)16 * NPTS * 16);     // 8192 i32

    float* loss = out + ZOUT;
    float* out_idx = out + ZOUT + 1;

    prep<<<768, 256, 0, stream>>>(z, emb, Zpk, Epk, e2, e2f);
    mfma_gemm<<<dim3(NPTS / 128, N_E / 1024), 256, 0, stream>>>(
        Epk, Zpk, e2f, tkey2);
    rescore<<<NPTS / 4, 256, 0, stream>>>(tkey2, z, emb, e2, idxf, out_idx, loss);
    quant_loss<<<1024, 256, 0, stream>>>(z, emb, idxf, out, loss);
}

// Round 10
// 260.640 us; speedup vs baseline: 1.4318x; 1.4318x over previous
//
#include <hip/hip_runtime.h>

// Problem constants (fixed by the reference).
#define D      256        // vq_embed_dim == C
#define N_E    16384      // codebook size
#define NPTS   8192       // B*H*W
#define ZOUT   2097152    // elements of z_hat_out
#define MARGIN 2.0e-2f    // cert/rescan margin ~6.6 sigma of bf16 pair error
#define BIGF   3.0e38f

typedef short bf16x8 __attribute__((ext_vector_type(8)));
typedef unsigned short us8 __attribute__((ext_vector_type(8)));
typedef float f32x16 __attribute__((ext_vector_type(16)));
typedef unsigned long long u64;

__device__ __forceinline__ unsigned short f2bf(float x) {  // RNE
    unsigned int u = __float_as_uint(x);
    return (unsigned short)((u + 0x7FFFu + ((u >> 16) & 1u)) >> 16);
}
__device__ __forceinline__ unsigned int mono(float f) {     // order-preserving
    unsigned int u = __float_as_uint(f);
    return (u & 0x80000000u) ? ~u : (u | 0x80000000u);
}
__device__ __forceinline__ float demono(unsigned int u) {
    return __uint_as_float((u & 0x80000000u) ? (u ^ 0x80000000u) : ~u);
}
__device__ __forceinline__ void gl_lds16(const void* g, void* l) {
    __builtin_amdgcn_global_load_lds(
        (const __attribute__((address_space(1))) unsigned int*)g,
        (__attribute__((address_space(3))) unsigned int*)l, 16, 0, 0);
}

// ---------------------------------------------------------------------------
// Fused prep. Blocks [0,256): z (32 points). Blocks [256,768): emb (32 codes).
// Zpk = bf16(-2z), Epk = bf16(emb) in fragment-chunk layout (chunk (g,ks):
// 64 lanes x 16B, lane = (row&31) + ((k&15)>>3)*32, elems k&7).
// e2[j] = |emb_j|^2 fp32; e2f = e2 permuted to MFMA C-row order.
// ---------------------------------------------------------------------------
__global__ __launch_bounds__(256) void prep(
    const float* __restrict__ z, const float* __restrict__ emb,
    unsigned short* __restrict__ Zpk, unsigned short* __restrict__ Epk,
    float* __restrict__ e2, float* __restrict__ e2f) {
    const int t = threadIdx.x;
    if (blockIdx.x < 256) {
        const int n0 = blockIdx.x * 32;
        const int p = t & 31, ks8 = t >> 5;     // 8 k-slabs of 32
        const int n = n0 + p;
        const int b = n >> 10, hw = n & 1023;
        const float* zb = z + (size_t)b * 262144 + hw;
        const int k0 = ks8 * 32;
        float v[32];
        #pragma unroll
        for (int kk = 0; kk < 32; ++kk)
            v[kk] = zb[(size_t)(k0 + kk) * 1024];   // coalesced in p
        const int g = n >> 5;
        #pragma unroll
        for (int i = 0; i < 4; ++i) {               // 4 us8 per 32-k slab
            us8 hv;
            #pragma unroll
            for (int c = 0; c < 8; ++c) hv[c] = f2bf(-2.0f * v[i * 8 + c]);
            const int kabs = k0 + i * 8;
            const int ks = kabs >> 4;
            const int l = p + ((kabs >> 3) & 1) * 32;
            *(us8*)(Zpk + ((size_t)(g * 16 + ks) * 64 + l) * 8) = hv;
        }
    } else {
        const int j0 = (blockIdx.x - 256) * 32;
        const int jl = t >> 3, q = t & 7;           // 8 k-slabs of 32
        const int jj = j0 + jl;
        const float* row = emb + (size_t)jj * D + q * 32;
        float v[32];
        float s = 0.f;
        #pragma unroll
        for (int i = 0; i < 8; ++i) {
            const float4 x = *(const float4*)(row + i * 4);
            v[i * 4] = x.x; v[i * 4 + 1] = x.y; v[i * 4 + 2] = x.z; v[i * 4 + 3] = x.w;
            s += x.x * x.x + x.y * x.y + x.z * x.z + x.w * x.w;
        }
        const int g = jj >> 5;
        #pragma unroll
        for (int i = 0; i < 4; ++i) {
            us8 hv;
            #pragma unroll
            for (int c = 0; c < 8; ++c) hv[c] = f2bf(v[i * 8 + c]);
            const int kabs = q * 32 + i * 8;
            const int ks = kabs >> 4;
            const int l = jl + ((kabs >> 3) & 1) * 32;
            *(us8*)(Epk + ((size_t)(g * 16 + ks) * 64 + l) * 8) = hv;
        }
        s += __shfl_xor(s, 1);
        s += __shfl_xor(s, 2);
        s += __shfl_xor(s, 4);
        if (q == 0) {
            e2[jj] = s;
            const int c5 = jj & 31;
            const int l5 = (c5 >> 2) & 1;
            const int r = (c5 & 3) | (((c5 >> 3) & 3) << 2);
            e2f[g * 32 + l5 * 16 + r] = s;
        }
    }
}

// ---------------------------------------------------------------------------
// GEMM + per-(point, 64-code group) top-2. Small-block/high-occupancy form:
// 64 points in LDS (32 KB) x 4 strips of 256 codes; 4 waves, wave wid owns
// a distinct 64-code column per strip; wave tile 64 codes x 64 pts =
// acc[2][2] (64 regs). Depth-1 prefetch, unroll 4 (anti-spill: no full
// unroll, no depth-2). LDS 40 KB -> 3-4 blocks/CU (12-16 waves).
// Key u64 = mono(m1)<<32 | dq<<16 | code16 staged in swizzled LDS keybuf,
// flushed as one contiguous 8 KB block.
// C/D layout: col(point)=lane&31, row(code)=(r&3)+8*(r>>2)+4*(lane>>5).
// ---------------------------------------------------------------------------
__global__ __launch_bounds__(256, 3) void mfma_gemm(
    const unsigned short* __restrict__ Epk, const unsigned short* __restrict__ Zpk,
    const float* __restrict__ e2f, u64* __restrict__ tkey2) {
    __shared__ unsigned short Zbuf[32 * 512];   // 32 KB
    __shared__ u64 keybuf[64 * 16];             // 8 KB (col-swizzled)

    const int tid = threadIdx.x, lane = tid & 63, wid = tid >> 6;
    const int c32 = lane & 31, l5 = lane >> 5;
    const int n0 = blockIdx.x * 64;
    const int cs0 = blockIdx.y * 1024;

    // Stage Z: 32 chunks (2 point-groups x 16 ks); wave wid stages 8.
    #pragma unroll
    for (int i = 0; i < 8; ++i) {
        const int c = wid * 8 + i;
        const int g = (n0 >> 5) + (c >> 4), ks = c & 15;
        gl_lds16(Zpk + ((size_t)(g * 16 + ks) * 64 + lane) * 8, Zbuf + c * 512);
    }
    __syncthreads();   // single drain per block

    const unsigned short* zb = Zbuf + lane * 8;

    for (int s = 0; s < 4; ++s) {
        const int cb = cs0 + s * 256 + wid * 64;   // this wave's 64 codes
        const unsigned short* eb = Epk + ((size_t)(cb >> 5) * 16) * 512 + lane * 8;

        f32x16 acc[2][2];
        const f32x16 z16 = {0.f};
        acc[0][0] = z16; acc[0][1] = z16; acc[1][0] = z16; acc[1][1] = z16;

        bf16x8 ec[2], pc[2];
        ec[0] = *(const bf16x8*)(eb);
        ec[1] = *(const bf16x8*)(eb + 16 * 512);
        pc[0] = *(const bf16x8*)(zb);
        pc[1] = *(const bf16x8*)(zb + 16 * 512);

        #pragma unroll 4
        for (int ks = 0; ks < 16; ++ks) {
            bf16x8 en[2], pn[2];
            if (ks < 15) {
                en[0] = *(const bf16x8*)(eb + (ks + 1) * 512);
                en[1] = *(const bf16x8*)(eb + (16 + ks + 1) * 512);
                pn[0] = *(const bf16x8*)(zb + (ks + 1) * 512);
                pn[1] = *(const bf16x8*)(zb + (16 + ks + 1) * 512);
            }
            acc[0][0] = __builtin_amdgcn_mfma_f32_32x32x16_bf16(
                ec[0], pc[0], acc[0][0], 0, 0, 0);
            acc[0][1] = __builtin_amdgcn_mfma_f32_32x32x16_bf16(
                ec[0], pc[1], acc[0][1], 0, 0, 0);
            acc[1][0] = __builtin_amdgcn_mfma_f32_32x32x16_bf16(
                ec[1], pc[0], acc[1][0], 0, 0, 0);
            acc[1][1] = __builtin_amdgcn_mfma_f32_32x32x16_bf16(
                ec[1], pc[1], acc[1][1], 0, 0, 0);
            if (ks < 15) {
                ec[0] = en[0]; ec[1] = en[1];
                pc[0] = pn[0]; pc[1] = pn[1];
            }
        }

        const int gs = s * 4 + wid;
        #pragma unroll
        for (int j = 0; j < 2; ++j) {
            float a1 = BIGF, a2 = BIGF;
            int ai = 0;
            #pragma unroll
            for (int i = 0; i < 2; ++i) {
                // v = e2f + acc, consumed immediately (no long-lived arrays).
                const float* ep = e2f + ((cb >> 5) + i) * 32 + l5 * 16;
                float v[16];
                #pragma unroll
                for (int rq = 0; rq < 4; ++rq) {
                    const float4 q = *(const float4*)(ep + rq * 4);
                    v[rq * 4 + 0] = q.x + acc[i][j][rq * 4 + 0];
                    v[rq * 4 + 1] = q.y + acc[i][j][rq * 4 + 1];
                    v[rq * 4 + 2] = q.z + acc[i][j][rq * 4 + 2];
                    v[rq * 4 + 3] = q.w + acc[i][j][rq * 4 + 3];
                }
                // Level 0: pairs (2rp, 2rp+1); code(2rp+1) = code(2rp)+1.
                float m1[8], m2[8];
                int i1[8];
                #pragma unroll
                for (int rp = 0; rp < 8; ++rp) {
                    const float a = v[2 * rp], b = v[2 * rp + 1];
                    const bool aw = a <= b;               // tie -> lower code
                    m1[rp] = aw ? a : b;
                    m2[rp] = aw ? b : a;
                    const int ca = ((2 * rp) & 3) + 8 * ((2 * rp) >> 2);
                    i1[rp] = aw ? ca : ca + 1;
                }
                // Levels 1..3: a-side always holds lower codes.
                #pragma unroll
                for (int st = 1; st < 8; st <<= 1)
                    #pragma unroll
                    for (int t8 = 0; t8 < 8; t8 += 2 * st) {
                        const bool aw = m1[t8] <= m1[t8 + st];
                        m2[t8] = fminf(aw ? m2[t8] : m2[t8 + st],
                                       aw ? m1[t8 + st] : m1[t8]);
                        m1[t8] = aw ? m1[t8] : m1[t8 + st];
                        i1[t8] = aw ? i1[t8] : i1[t8 + st];
                    }
                const float f1 = m1[0], f2 = m2[0];
                const int fi = i * 32 + i1[0] + 4 * l5;
                const bool w = f1 < a1;   // i ascending = codes ascending
                a2 = fminf(w ? a1 : a2, w ? f2 : f1);
                a1 = w ? f1 : a1;
                ai = w ? fi : ai;
            }
            // Cross-half merge (tie degrades m2 -> uncertified -> exact path).
            const float o1 = __shfl_xor(a1, 32);
            const float o2 = __shfl_xor(a2, 32);
            const int oi = __shfl_xor(ai, 32);
            if (o1 < a1) { a2 = fminf(a1, o2); a1 = o1; ai = oi; }
            else         { a2 = fminf(a2, o1); }
            if (l5 == 0) {
                const unsigned int dq = (unsigned int)fminf(
                    fmaxf((a2 - a1) * 4096.0f, 0.0f), 65535.0f);
                const unsigned int code = (unsigned int)(cb + ai);
                const int p = j * 32 + c32;
                keybuf[p * 16 + ((gs + p) & 15)] =
                    ((u64)mono(a1) << 32) | (dq << 16) | code;
            }
        }
    }

    __syncthreads();
    // Flush: contiguous 8 KB block write, de-swizzling columns.
    u64* dst = tkey2 + (size_t)blockIdx.y * (NPTS * 16) + (size_t)n0 * 16;
    #pragma unroll
    for (int it = 0; it < 4; ++it) {
        const int idx = it * 256 + tid;
        const int p = idx >> 4, gl = idx & 15;
        dst[idx] = keybuf[p * 16 + ((gl + p) & 15)];
    }
}

// ---------------------------------------------------------------------------
// Rescore with certification. One wave per point. Lane l holds 4 group keys.
// d1/idx from global min key; d2 from second-best estimate. Certified if
// d2-d1 > MARGIN; else exact fp32 rescan of qualifying 64-code groups,
// lane-cooperative (coalesced 1KB/code rows, butterfly-reduced dot).
// ---------------------------------------------------------------------------
__global__ __launch_bounds__(256) void rescore(
    const u64* __restrict__ tkey2, const float* __restrict__ z,
    const float* __restrict__ emb, const float* __restrict__ e2,
    int* __restrict__ idxf, float* __restrict__ out_idx,
    float* __restrict__ loss) {
    const int tid = threadIdx.x, lane = tid & 63, w = tid >> 6;
    const int n = blockIdx.x * 4 + w;
    if (blockIdx.x == 0 && tid == 0) loss[0] = 0.f;

    const int gb = lane >> 2, q4 = lane & 3;
    u64 kv[4];
    {
        const u64* src = tkey2 + (size_t)gb * (NPTS * 16) + (size_t)n * 16 + q4 * 4;
        #pragma unroll
        for (int qq = 0; qq < 4; ++qq) kv[qq] = src[qq];
    }
    u64 k1 = kv[0];
    #pragma unroll
    for (int qq = 1; qq < 4; ++qq) k1 = kv[qq] < k1 ? kv[qq] : k1;
    #pragma unroll
    for (int st = 1; st < 64; st <<= 1) {
        const u64 o = __shfl_xor(k1, st);
        if (o < k1) k1 = o;
    }
    const float d1 = demono((unsigned int)(k1 >> 32));
    float d2 = BIGF;
    #pragma unroll
    for (int qq = 0; qq < 4; ++qq) {
        const float m1g = demono((unsigned int)(kv[qq] >> 32));
        const float cand = (kv[qq] == k1)
            ? d1 + (float)((kv[qq] >> 16) & 0xFFFFull) * (1.0f / 4096.0f)
            : m1g;
        d2 = fminf(d2, cand);
    }
    #pragma unroll
    for (int st = 1; st < 64; st <<= 1) d2 = fminf(d2, __shfl_xor(d2, st));

    int bi;
    if (d2 - d1 > MARGIN) {
        bi = (int)(unsigned int)(k1 & 0xFFFFull);       // certified
    } else {
        // Lane l holds residual components k = 4l..4l+3.
        const int b = n >> 10, hw = n & 1023;
        float r4[4];
        #pragma unroll
        for (int kk = 0; kk < 4; ++kk)
            r4[kk] = z[(size_t)b * 262144 + (size_t)(lane * 4 + kk) * 1024 + hw];
        const float thresh = d1 + MARGIN;
        u64 best = ~0ull;
        #pragma unroll
        for (int qq = 0; qq < 4; ++qq) {
            u64 mask = __ballot(demono((unsigned int)(kv[qq] >> 32)) <= thresh);
            while (mask) {
                const int bit = (int)__builtin_ctzll(mask);
                mask &= mask - 1;
                const int grp = (bit >> 2) * 16 + (bit & 3) * 4 + qq;
                const float* ebase = emb + (size_t)grp * (64 * D) + lane * 4;
                for (int ci = 0; ci < 64; ++ci) {
                    const float4 ev = *(const float4*)(ebase + ci * D);
                    float s = r4[0] * ev.x + r4[1] * ev.y +
                              r4[2] * ev.z + r4[3] * ev.w;
                    #pragma unroll
                    for (int st = 1; st < 64; st <<= 1) s += __shfl_xor(s, st);
                    const int code = grp * 64 + ci;
                    const float d = e2[code] - 2.0f * s;
                    const u64 key = ((u64)mono(d) << 32) | (unsigned int)code;
                    if (key < best) best = key;   // uniform across the wave
                }
            }
        }
        bi = (int)(unsigned int)(best & 0xFFFFFFFFull);
    }
    if (lane == 0) {
        idxf[n] = bi;
        const int b = n >> 10, hw = n & 1023;
        const float fv = (float)bi;
        #pragma unroll
        for (int sc = 0; sc < 4; ++sc) out_idx[b * 4096 + sc * 1024 + hw] = fv;
    }
}

// ---------------------------------------------------------------------------
// Gather q = emb[idx]; z_hat_out = z + (4q - z); loss accumulation.
// 1024 blocks: (4 c-tiles of 64) x (8 b x 32 hw-tiles). 256 thr = 32 hw x 8 cg.
// ---------------------------------------------------------------------------
__global__ __launch_bounds__(256) void quant_loss(
    const float* __restrict__ z, const float* __restrict__ emb,
    const int* __restrict__ idxf, float* __restrict__ out,
    float* __restrict__ loss) {
    __shared__ int idx_l[32];
    __shared__ float wsum[4];
    const int blk = blockIdx.x;
    const int c0 = (blk >> 8) * 64;
    const int rem = blk & 255;
    const int b = rem >> 5, hw0 = (rem & 31) * 32;
    const int t = threadIdx.x, hw_l = t & 31, cg = t >> 5;
    if (t < 32) idx_l[t] = idxf[b * 1024 + hw0 + t];
    __syncthreads();
    const int j = idx_l[hw_l];
    const float* er = emb + (size_t)j * D + c0 + cg * 8;
    const float4 q0 = *(const float4*)er;
    const float4 q1 = *(const float4*)(er + 4);
    const float qv[8] = {q0.x, q0.y, q0.z, q0.w, q1.x, q1.y, q1.z, q1.w};
    float e = 0.f;
    #pragma unroll
    for (int cc = 0; cc < 8; ++cc) {
        const int c = c0 + cg * 8 + cc;
        const size_t zi = (size_t)b * 262144 + (size_t)c * 1024 + hw0 + hw_l;
        const float zv = z[zi];
        const float q = qv[cc];
        const float zh = ((q + q) + q) + q;   // mimic 4-step accumulation
        out[zi] = zv + (zh - zv);
        e += 30.0f * q * q - 20.0f * q * zv + 4.0f * zv * zv;
    }
    #pragma unroll
    for (int off = 32; off > 0; off >>= 1) e += __shfl_down(e, off);
    if ((t & 63) == 0) wsum[t >> 6] = e;
    __syncthreads();
    if (t == 0) {
        const float s = wsum[0] + wsum[1] + wsum[2] + wsum[3];
        atomicAdd(loss, s * (0.3125f / 2097152.0f));
    }
}

// ---------------------------------------------------------------------------
extern "C" void kernel_launch(void* const* d_in, const int* in_sizes, int n_in,
                              void* d_out, int out_size, void* d_ws, size_t ws_size,
                              hipStream_t stream) {
    const float* z = (const float*)d_in[0];     // [8,256,32,32]
    const float* emb = (const float*)d_in[1];   // [16384,256]
    float* out = (float*)d_out;                 // z_hat_out | loss | total_idx

    // Workspace (~29.5 MB)
    unsigned short* Zpk = (unsigned short*)d_ws;            // 8192*256 bf16
    unsigned short* Epk = Zpk + (size_t)NPTS * D;           // 16384*256 bf16
    float* e2 = (float*)(Epk + (size_t)N_E * D);            // 16384 f32
    float* e2f = e2 + N_E;                                  // 16384 f32
    u64* tkey2 = (u64*)(e2f + N_E);                         // 16*8192*16 u64
    int* idxf = (int*)(tkey2 + (size_t)16 * NPTS * 16);     // 8192 i32

    float* loss = out + ZOUT;
    float* out_idx = out + ZOUT + 1;

    prep<<<768, 256, 0, stream>>>(z, emb, Zpk, Epk, e2, e2f);
    mfma_gemm<<<dim3(NPTS / 64, N_E / 1024), 256, 0, stream>>>(
        Epk, Zpk, e2f, tkey2);
    rescore<<<NPTS / 4, 256, 0, stream>>>(tkey2, z, emb, e2, idxf, out_idx, loss);
    quant_loss<<<1024, 256, 0, stream>>>(z, emb, idxf, out, loss);
}